// Round 6
// baseline (69.823 us; speedup 1.0000x reference)
//
#include <hip/hip_runtime.h>
#include <math.h>

constexpr int kN = 4096;
constexpr int kD = 4;
constexpr int kB = 2;
constexpr int kBlock = 256;
constexpr int kRowsPerWave = 2;
constexpr int kWaves = kBlock / 64;                      // 4
constexpr int kRowsPerBlock = kRowsPerWave * kWaves;     // 8
constexpr int kIters = kN / (64 * 4);                    // 16 stages (4 j/lane)

// Precompute sin/cos(theta) as float4-per-j tables: sinT[b*N+j] = {s_d0..s_d3}.
__global__ __launch_bounds__(256)
void table_kernel(const float* __restrict__ theta,
                  float4* __restrict__ sinT, float4* __restrict__ cosT)
{
    const int idx = blockIdx.x * blockDim.x + threadIdx.x;   // over B*N
    const float4 t4 = *reinterpret_cast<const float4*>(&theta[(size_t)idx * kD]);
    float4 s4, c4;
    __sincosf(t4.x, &s4.x, &c4.x);
    __sincosf(t4.y, &s4.y, &c4.y);
    __sincosf(t4.z, &s4.z, &c4.z);
    __sincosf(t4.w, &s4.w, &c4.w);
    sinT[idx] = s4;
    cosT[idx] = c4;
}

// 2 rows/wave, no LDS, no barriers. W/alpha (HBM) register double-buffered;
// sin/cos tables (L1/L2-resident) loaded inline in the compute stage.
template <bool USE_TABLE>
__global__ __launch_bounds__(kBlock)
void kuramoto_kernel(const float* __restrict__ theta,
                     const float* __restrict__ gam,
                     const float* __restrict__ W,
                     const float* __restrict__ alpha,
                     const float4* __restrict__ sinT,
                     const float4* __restrict__ cosT,
                     float* __restrict__ out)
{
    const int tid  = threadIdx.x;
    const int wave = tid >> 6;
    const int lane = tid & 63;

    const int row0 = blockIdx.x * kRowsPerBlock + wave * kRowsPerWave;
    const int b    = row0 >> 12;                          // row0 / kN

    const float* __restrict__ W0 = W     + (size_t)(row0 + 0) * kN;
    const float* __restrict__ W1 = W     + (size_t)(row0 + 1) * kN;
    const float* __restrict__ A0 = alpha + (size_t)(row0 + 0) * kN;
    const float* __restrict__ A1 = alpha + (size_t)(row0 + 1) * kN;
    const float4* __restrict__ sB = sinT + (size_t)b * kN;
    const float4* __restrict__ cB = cosT + (size_t)b * kN;
    const float* thetaB = theta + (size_t)b * kN * kD;

    float U[kRowsPerWave][kD];
    float V[kRowsPerWave][kD];
    #pragma unroll
    for (int r = 0; r < kRowsPerWave; ++r)
        #pragma unroll
        for (int d = 0; d < kD; ++d) { U[r][d] = 0.f; V[r][d] = 0.f; }

    // Prefetch only the HBM streams: W/alpha for 2 rows, 4 j's per lane.
    auto prefetch = [&](int k, float4 (&w)[2], float4 (&a)[2]) {
        const int jb = k * 256 + lane * 4;
        w[0] = *reinterpret_cast<const float4*>(&W0[jb]);
        w[1] = *reinterpret_cast<const float4*>(&W1[jb]);
        a[0] = *reinterpret_cast<const float4*>(&A0[jb]);
        a[1] = *reinterpret_cast<const float4*>(&A1[jb]);
    };

    auto compute = [&](int k, const float4 (&w)[2], const float4 (&a)[2]) {
        const int jb = k * 256 + lane * 4;
        float sv[4][kD], cv[4][kD];
        if constexpr (USE_TABLE) {
            #pragma unroll
            for (int u = 0; u < 4; ++u) {
                const float4 s4 = sB[jb + u];
                const float4 c4 = cB[jb + u];
                sv[u][0] = s4.x; sv[u][1] = s4.y; sv[u][2] = s4.z; sv[u][3] = s4.w;
                cv[u][0] = c4.x; cv[u][1] = c4.y; cv[u][2] = c4.z; cv[u][3] = c4.w;
            }
        } else {
            #pragma unroll
            for (int u = 0; u < 4; ++u) {
                const float4 t4 = *reinterpret_cast<const float4*>(&thetaB[(size_t)(jb + u) * kD]);
                __sincosf(t4.x, &sv[u][0], &cv[u][0]);
                __sincosf(t4.y, &sv[u][1], &cv[u][1]);
                __sincosf(t4.z, &sv[u][2], &cv[u][2]);
                __sincosf(t4.w, &sv[u][3], &cv[u][3]);
            }
        }
        #pragma unroll
        for (int r = 0; r < kRowsPerWave; ++r) {
            const float wv[4] = {w[r].x, w[r].y, w[r].z, w[r].w};
            const float av[4] = {a[r].x, a[r].y, a[r].z, a[r].w};
            #pragma unroll
            for (int u = 0; u < 4; ++u) {
                float sa, ca;
                __sincosf(av[u], &sa, &ca);
                const float P = wv[u] * ca;
                const float Q = wv[u] * sa;
                U[r][0] = fmaf(P, sv[u][0], fmaf(-Q, cv[u][0], U[r][0]));
                V[r][0] = fmaf(P, cv[u][0], fmaf( Q, sv[u][0], V[r][0]));
                U[r][1] = fmaf(P, sv[u][1], fmaf(-Q, cv[u][1], U[r][1]));
                V[r][1] = fmaf(P, cv[u][1], fmaf( Q, sv[u][1], V[r][1]));
                U[r][2] = fmaf(P, sv[u][2], fmaf(-Q, cv[u][2], U[r][2]));
                V[r][2] = fmaf(P, cv[u][2], fmaf( Q, sv[u][2], V[r][2]));
                U[r][3] = fmaf(P, sv[u][3], fmaf(-Q, cv[u][3], U[r][3]));
                V[r][3] = fmaf(P, cv[u][3], fmaf( Q, sv[u][3], V[r][3]));
            }
        }
    };

    float4 wA[2], aA[2], wX[2], aX[2];

    prefetch(0, wA, aA);
    for (int k = 0; k < kIters - 2; k += 2) {
        prefetch(k + 1, wX, aX);
        __builtin_amdgcn_sched_barrier(0);     // pin prefetch above compute
        compute(k, wA, aA);
        prefetch(k + 2, wA, aA);
        __builtin_amdgcn_sched_barrier(0);
        compute(k + 1, wX, aX);
    }
    prefetch(kIters - 1, wX, aX);
    __builtin_amdgcn_sched_barrier(0);
    compute(kIters - 2, wA, aA);
    compute(kIters - 1, wX, aX);

    // Wave-wide butterfly reduction (16 accumulators per wave).
    #pragma unroll
    for (int m = 1; m < 64; m <<= 1) {
        #pragma unroll
        for (int r = 0; r < kRowsPerWave; ++r)
            #pragma unroll
            for (int d = 0; d < kD; ++d) {
                U[r][d] += __shfl_xor(U[r][d], m, 64);
                V[r][d] += __shfl_xor(V[r][d], m, 64);
            }
    }

    // Lane r writes row row0+r (constant register indices only).
    #pragma unroll
    for (int r = 0; r < kRowsPerWave; ++r) {
        if (lane == r) {
            const int row = row0 + r;
            const float4 t4 = *reinterpret_cast<const float4*>(&theta[(size_t)row * kD]);
            const float4 g4 = *reinterpret_cast<const float4*>(&gam[(size_t)row * kD]);
            const float tv[4] = {t4.x, t4.y, t4.z, t4.w};
            const float gv[4] = {g4.x, g4.y, g4.z, g4.w};
            constexpr float scale = 1.0f / (float)kN;     // GLOBAL_COUPLING / N
            float x[4];
            float nsq = 0.f;
            #pragma unroll
            for (int d = 0; d < kD; ++d) {
                float si, ci;
                __sincosf(tv[d], &si, &ci);
                const float coup = scale * (ci * U[r][d] - si * V[r][d]);
                x[d] = gv[d] + coup;      // gamma + coupling (drive cancels theta)
                nsq += x[d] * x[d];
            }
            const float inv = 1.0f / fmaxf(sqrtf(nsq), 1e-6f);
            float4 o;
            o.x = x[0] * inv; o.y = x[1] * inv; o.z = x[2] * inv; o.w = x[3] * inv;
            *reinterpret_cast<float4*>(&out[(size_t)row * kD]) = o;
        }
    }
}

extern "C" void kernel_launch(void* const* d_in, const int* in_sizes, int n_in,
                              void* d_out, int out_size, void* d_ws, size_t ws_size,
                              hipStream_t stream) {
    const float* theta = (const float*)d_in[0];   // (B,N,D) f32
    const float* gam   = (const float*)d_in[1];   // (B,N,D) f32
    const float* W     = (const float*)d_in[2];   // (B,N,N) f32
    const float* alpha = (const float*)d_in[3];   // (B,N,N) f32
    float* out = (float*)d_out;                   // (B,N,D) f32

    const int totalRows = in_sizes[0] / kD;           // B*N = 8192
    const int nblocks = totalRows / kRowsPerBlock;    // 1024
    const size_t tabEntries = (size_t)kB * kN;        // 8192 float4 per table
    const size_t needWs = 2 * tabEntries * sizeof(float4);   // 256 KB

    if (ws_size >= needWs) {
        float4* sinT = (float4*)d_ws;
        float4* cosT = sinT + tabEntries;
        table_kernel<<<(int)(tabEntries / 256), 256, 0, stream>>>(theta, sinT, cosT);
        kuramoto_kernel<true><<<nblocks, kBlock, 0, stream>>>(
            theta, gam, W, alpha, sinT, cosT, out);
    } else {
        kuramoto_kernel<false><<<nblocks, kBlock, 0, stream>>>(
            theta, gam, W, alpha, nullptr, nullptr, out);
    }
}

// Round 7
// 67.328 us; speedup vs baseline: 1.0370x; 1.0370x over previous
//
#include <hip/hip_runtime.h>
#include <math.h>

constexpr int kN = 4096;
constexpr int kD = 4;
constexpr int kB = 2;
constexpr int kBlock = 256;
constexpr int kRowsPerWave = 4;
constexpr int kJSplit = 2;                               // waves per row-group
constexpr int kRowGroups = 2;                            // row-groups per block
constexpr int kRowsPerBlock = kRowsPerWave * kRowGroups; // 8
constexpr int kJPerWave = kN / kJSplit;                  // 2048
constexpr int kIters = kJPerWave / 256;                  // 8 stages (4 j/lane)

// Precompute sin/cos(theta) as float4-per-j tables: sinT[b*N+j] = {s_d0..s_d3}.
__global__ __launch_bounds__(256)
void table_kernel(const float* __restrict__ theta,
                  float4* __restrict__ sinT, float4* __restrict__ cosT)
{
    const int idx = blockIdx.x * blockDim.x + threadIdx.x;   // over B*N
    const float4 t4 = *reinterpret_cast<const float4*>(&theta[(size_t)idx * kD]);
    float4 s4, c4;
    __sincosf(t4.x, &s4.x, &c4.x);
    __sincosf(t4.y, &s4.y, &c4.y);
    __sincosf(t4.z, &s4.z, &c4.z);
    __sincosf(t4.w, &s4.w, &c4.w);
    sinT[idx] = s4;
    cosT[idx] = c4;
}

// 4 rows/wave, j-split x2 (two waves share rows, disjoint j-halves).
// All streams register-double-buffered; LDS only for the final combine.
template <bool USE_TABLE>
__global__ __launch_bounds__(kBlock)
void kuramoto_kernel(const float* __restrict__ theta,
                     const float* __restrict__ gam,
                     const float* __restrict__ W,
                     const float* __restrict__ alpha,
                     const float4* __restrict__ sinT,
                     const float4* __restrict__ cosT,
                     float* __restrict__ out)
{
    __shared__ float sRed[kRowGroups][kJSplit][kRowsPerWave][kD][2];

    const int tid  = threadIdx.x;
    const int wave = tid >> 6;
    const int lane = tid & 63;
    const int rg   = wave >> 1;        // row-group within block
    const int jh   = wave & 1;         // j-half

    const int row0  = blockIdx.x * kRowsPerBlock + rg * kRowsPerWave;
    const int b     = row0 >> 12;      // row0 / kN
    const int jbase = jh * kJPerWave;

    const float* Wr[kRowsPerWave];
    const float* Ar[kRowsPerWave];
    #pragma unroll
    for (int r = 0; r < kRowsPerWave; ++r) {
        Wr[r] = W     + (size_t)(row0 + r) * kN + jbase;
        Ar[r] = alpha + (size_t)(row0 + r) * kN + jbase;
    }
    const float4* __restrict__ sB = sinT + (size_t)b * kN + jbase;
    const float4* __restrict__ cB = cosT + (size_t)b * kN + jbase;
    const float* thetaB = theta + ((size_t)b * kN + jbase) * kD;

    float U[kRowsPerWave][kD];
    float V[kRowsPerWave][kD];
    #pragma unroll
    for (int r = 0; r < kRowsPerWave; ++r)
        #pragma unroll
        for (int d = 0; d < kD; ++d) { U[r][d] = 0.f; V[r][d] = 0.f; }

    // One stage: 4 consecutive j per lane; prefetch W/alpha (HBM) AND tables.
    auto load_stage = [&](int k, float4 (&s)[4], float4 (&c)[4],
                          float4 (&w)[4], float4 (&a)[4]) {
        const int jb = k * 256 + lane * 4;
        #pragma unroll
        for (int u = 0; u < 4; ++u) {
            if constexpr (USE_TABLE) {
                s[u] = sB[jb + u];
                c[u] = cB[jb + u];
            } else {
                s[u] = *reinterpret_cast<const float4*>(&thetaB[(size_t)(jb + u) * kD]);
            }
        }
        #pragma unroll
        for (int r = 0; r < kRowsPerWave; ++r) {
            w[r] = *reinterpret_cast<const float4*>(&Wr[r][jb]);
            a[r] = *reinterpret_cast<const float4*>(&Ar[r][jb]);
        }
    };

    auto compute_stage = [&](const float4 (&s)[4], const float4 (&c)[4],
                             const float4 (&w)[4], const float4 (&a)[4]) {
        float sv[4][kD], cv[4][kD];
        #pragma unroll
        for (int u = 0; u < 4; ++u) {
            if constexpr (USE_TABLE) {
                sv[u][0] = s[u].x; sv[u][1] = s[u].y; sv[u][2] = s[u].z; sv[u][3] = s[u].w;
                cv[u][0] = c[u].x; cv[u][1] = c[u].y; cv[u][2] = c[u].z; cv[u][3] = c[u].w;
            } else {
                __sincosf(s[u].x, &sv[u][0], &cv[u][0]);
                __sincosf(s[u].y, &sv[u][1], &cv[u][1]);
                __sincosf(s[u].z, &sv[u][2], &cv[u][2]);
                __sincosf(s[u].w, &sv[u][3], &cv[u][3]);
            }
        }
        #pragma unroll
        for (int r = 0; r < kRowsPerWave; ++r) {
            const float wv[4] = {w[r].x, w[r].y, w[r].z, w[r].w};
            const float av[4] = {a[r].x, a[r].y, a[r].z, a[r].w};
            #pragma unroll
            for (int u = 0; u < 4; ++u) {
                float sa, ca;
                __sincosf(av[u], &sa, &ca);
                const float P = wv[u] * ca;
                const float Q = wv[u] * sa;
                U[r][0] = fmaf(P, sv[u][0], fmaf(-Q, cv[u][0], U[r][0]));
                V[r][0] = fmaf(P, cv[u][0], fmaf( Q, sv[u][0], V[r][0]));
                U[r][1] = fmaf(P, sv[u][1], fmaf(-Q, cv[u][1], U[r][1]));
                V[r][1] = fmaf(P, cv[u][1], fmaf( Q, sv[u][1], V[r][1]));
                U[r][2] = fmaf(P, sv[u][2], fmaf(-Q, cv[u][2], U[r][2]));
                V[r][2] = fmaf(P, cv[u][2], fmaf( Q, sv[u][2], V[r][2]));
                U[r][3] = fmaf(P, sv[u][3], fmaf(-Q, cv[u][3], U[r][3]));
                V[r][3] = fmaf(P, cv[u][3], fmaf( Q, sv[u][3], V[r][3]));
            }
        }
    };

    float4 sA[4], cA[4], wA[4], aA[4];
    float4 sX[4], cX[4], wX[4], aX[4];

    load_stage(0, sA, cA, wA, aA);
    for (int k = 0; k < kIters - 2; k += 2) {
        load_stage(k + 1, sX, cX, wX, aX);
        __builtin_amdgcn_sched_barrier(0);     // pin prefetch above compute
        compute_stage(sA, cA, wA, aA);
        load_stage(k + 2, sA, cA, wA, aA);
        __builtin_amdgcn_sched_barrier(0);
        compute_stage(sX, cX, wX, aX);
    }
    load_stage(kIters - 1, sX, cX, wX, aX);
    __builtin_amdgcn_sched_barrier(0);
    compute_stage(sA, cA, wA, aA);
    compute_stage(sX, cX, wX, aX);

    // Wave-wide butterfly reduction (32 accumulators per wave).
    #pragma unroll
    for (int m = 1; m < 64; m <<= 1) {
        #pragma unroll
        for (int r = 0; r < kRowsPerWave; ++r)
            #pragma unroll
            for (int d = 0; d < kD; ++d) {
                U[r][d] += __shfl_xor(U[r][d], m, 64);
                V[r][d] += __shfl_xor(V[r][d], m, 64);
            }
    }

    // Publish this wave's partials (all constant register indices).
    if (lane == 0) {
        #pragma unroll
        for (int r = 0; r < kRowsPerWave; ++r)
            #pragma unroll
            for (int d = 0; d < kD; ++d) {
                sRed[rg][jh][r][d][0] = U[r][d];
                sRed[rg][jh][r][d][1] = V[r][d];
            }
    }
    __syncthreads();

    // j-half 0 waves combine with partner partials and write rows.
    if (jh == 0) {
        #pragma unroll
        for (int r = 0; r < kRowsPerWave; ++r) {
            if (lane == r) {
                const int row = row0 + r;
                const float4 t4 = *reinterpret_cast<const float4*>(&theta[(size_t)row * kD]);
                const float4 g4 = *reinterpret_cast<const float4*>(&gam[(size_t)row * kD]);
                const float tv[4] = {t4.x, t4.y, t4.z, t4.w};
                const float gv[4] = {g4.x, g4.y, g4.z, g4.w};
                constexpr float scale = 1.0f / (float)kN;  // GLOBAL_COUPLING / N
                float x[4];
                float nsq = 0.f;
                #pragma unroll
                for (int d = 0; d < kD; ++d) {
                    const float Uf = U[r][d] + sRed[rg][1][r][d][0];
                    const float Vf = V[r][d] + sRed[rg][1][r][d][1];
                    float si, ci;
                    __sincosf(tv[d], &si, &ci);
                    const float coup = scale * (ci * Uf - si * Vf);
                    x[d] = gv[d] + coup;   // gamma + coupling (drive cancels theta)
                    nsq += x[d] * x[d];
                }
                const float inv = 1.0f / fmaxf(sqrtf(nsq), 1e-6f);
                float4 o;
                o.x = x[0] * inv; o.y = x[1] * inv; o.z = x[2] * inv; o.w = x[3] * inv;
                *reinterpret_cast<float4*>(&out[(size_t)row * kD]) = o;
            }
        }
    }
}

extern "C" void kernel_launch(void* const* d_in, const int* in_sizes, int n_in,
                              void* d_out, int out_size, void* d_ws, size_t ws_size,
                              hipStream_t stream) {
    const float* theta = (const float*)d_in[0];   // (B,N,D) f32
    const float* gam   = (const float*)d_in[1];   // (B,N,D) f32
    const float* W     = (const float*)d_in[2];   // (B,N,N) f32
    const float* alpha = (const float*)d_in[3];   // (B,N,N) f32
    float* out = (float*)d_out;                   // (B,N,D) f32

    const int totalRows = in_sizes[0] / kD;           // B*N = 8192
    const int nblocks = totalRows / kRowsPerBlock;    // 1024
    const size_t tabEntries = (size_t)kB * kN;        // 8192 float4 per table
    const size_t needWs = 2 * tabEntries * sizeof(float4);   // 256 KB

    if (ws_size >= needWs) {
        float4* sinT = (float4*)d_ws;
        float4* cosT = sinT + tabEntries;
        table_kernel<<<(int)(tabEntries / 256), 256, 0, stream>>>(theta, sinT, cosT);
        kuramoto_kernel<true><<<nblocks, kBlock, 0, stream>>>(
            theta, gam, W, alpha, sinT, cosT, out);
    } else {
        kuramoto_kernel<false><<<nblocks, kBlock, 0, stream>>>(
            theta, gam, W, alpha, nullptr, nullptr, out);
    }
}

// Round 8
// 54.173 us; speedup vs baseline: 1.2889x; 1.2428x over previous
//
#include <hip/hip_runtime.h>
#include <math.h>

constexpr int kN = 4096;
constexpr int kD = 4;
constexpr int kB = 2;
constexpr int kBlock = 256;
constexpr int kRowsPerWave = 2;
constexpr int kRowsPerBlock = 8;       // 4 waves x 2 rows
constexpr int kTJ = 1024;              // j per LDS tile
constexpr int kTiles = kN / kTJ;       // 4
constexpr int kTotalStages = kN / 256; // 16 (256 j per stage, 4 j/lane)

// Precompute sin/cos(theta) as float4-per-j tables: sinT[b*N+j] = {s_d0..s_d3}.
__global__ __launch_bounds__(256)
void table_kernel(const float* __restrict__ theta,
                  float4* __restrict__ sinT, float4* __restrict__ cosT)
{
    const int idx = blockIdx.x * blockDim.x + threadIdx.x;   // over B*N
    const float4 t4 = *reinterpret_cast<const float4*>(&theta[(size_t)idx * kD]);
    float4 s4, c4;
    __sincosf(t4.x, &s4.x, &c4.x);
    __sincosf(t4.y, &s4.y, &c4.y);
    __sincosf(t4.z, &s4.z, &c4.z);
    __sincosf(t4.w, &s4.w, &c4.w);
    sinT[idx] = s4;
    cosT[idx] = c4;
}

// LDS-tiled tables (u-permuted, conflict-free) + reg-double-buffered W/alpha.
// Layout: tile-relative jr stored at sS[jr&3][jr>>2]; stage k, lane L reads
// jr = k*256 + 4L + u at sS[u][k*64+L] -> ds addr stride 16B across lanes.
template <bool USE_TABLE>
__global__ __launch_bounds__(kBlock)
void kuramoto_kernel(const float* __restrict__ theta,
                     const float* __restrict__ gam,
                     const float* __restrict__ W,
                     const float* __restrict__ alpha,
                     const float4* __restrict__ sinT,
                     const float4* __restrict__ cosT,
                     float* __restrict__ out)
{
    __shared__ __align__(16) float4 sS[4][kTJ / 4];   // 16 KB
    __shared__ __align__(16) float4 sC[4][kTJ / 4];   // 16 KB

    const int tid  = threadIdx.x;
    const int wave = tid >> 6;
    const int lane = tid & 63;

    const int row0 = blockIdx.x * kRowsPerBlock;
    const int b    = row0 >> 12;
    const int r0   = row0 + wave * kRowsPerWave;

    const float* __restrict__ W0 = W     + (size_t)r0 * kN;
    const float* __restrict__ W1 = W0 + kN;
    const float* __restrict__ A0 = alpha + (size_t)r0 * kN;
    const float* __restrict__ A1 = A0 + kN;
    const float4* __restrict__ sT = sinT + (size_t)b * kN;
    const float4* __restrict__ cT = cosT + (size_t)b * kN;
    const float* __restrict__ thetaB = theta + (size_t)b * kN * kD;

    float U0[4] = {0,0,0,0}, V0[4] = {0,0,0,0};
    float U1[4] = {0,0,0,0}, V1[4] = {0,0,0,0};

    auto pf = [&](int g, float4& w0, float4& w1, float4& a0, float4& a1) {
        const int j = g * 256 + lane * 4;
        w0 = *reinterpret_cast<const float4*>(&W0[j]);
        w1 = *reinterpret_cast<const float4*>(&W1[j]);
        a0 = *reinterpret_cast<const float4*>(&A0[j]);
        a1 = *reinterpret_cast<const float4*>(&A1[j]);
    };

    auto stage_tile = [&](int tile) {
        const int J0 = tile * kTJ;
        if constexpr (USE_TABLE) {
            const float4 v0 = sT[J0 + 4 * tid + 0];
            const float4 v1 = sT[J0 + 4 * tid + 1];
            const float4 v2 = sT[J0 + 4 * tid + 2];
            const float4 v3 = sT[J0 + 4 * tid + 3];
            sS[0][tid] = v0; sS[1][tid] = v1; sS[2][tid] = v2; sS[3][tid] = v3;
            const float4 u0 = cT[J0 + 4 * tid + 0];
            const float4 u1 = cT[J0 + 4 * tid + 1];
            const float4 u2 = cT[J0 + 4 * tid + 2];
            const float4 u3 = cT[J0 + 4 * tid + 3];
            sC[0][tid] = u0; sC[1][tid] = u1; sC[2][tid] = u2; sC[3][tid] = u3;
        } else {
            #pragma unroll
            for (int u = 0; u < 4; ++u) {
                const int j = J0 + 4 * tid + u;
                const float4 t4 = *reinterpret_cast<const float4*>(&thetaB[(size_t)j * kD]);
                float4 sv, cv;
                __sincosf(t4.x, &sv.x, &cv.x);
                __sincosf(t4.y, &sv.y, &cv.y);
                __sincosf(t4.z, &sv.z, &cv.z);
                __sincosf(t4.w, &sv.w, &cv.w);
                sS[u][tid] = sv; sC[u][tid] = cv;
            }
        }
    };

    auto compute = [&](int k, const float4 w0, const float4 w1,
                       const float4 a0, const float4 a1) {
        const int idx = k * 64 + lane;
        // Issue all 8 ds_read_b128 first; latency hides under the sincos chain.
        const float4 s0 = sS[0][idx], s1 = sS[1][idx], s2 = sS[2][idx], s3 = sS[3][idx];
        const float4 c0 = sC[0][idx], c1 = sC[1][idx], c2 = sC[2][idx], c3 = sC[3][idx];
        float P[8], Q[8];
        float sa, ca;
        __sincosf(a0.x, &sa, &ca); P[0] = w0.x * ca; Q[0] = w0.x * sa;
        __sincosf(a0.y, &sa, &ca); P[1] = w0.y * ca; Q[1] = w0.y * sa;
        __sincosf(a0.z, &sa, &ca); P[2] = w0.z * ca; Q[2] = w0.z * sa;
        __sincosf(a0.w, &sa, &ca); P[3] = w0.w * ca; Q[3] = w0.w * sa;
        __sincosf(a1.x, &sa, &ca); P[4] = w1.x * ca; Q[4] = w1.x * sa;
        __sincosf(a1.y, &sa, &ca); P[5] = w1.y * ca; Q[5] = w1.y * sa;
        __sincosf(a1.z, &sa, &ca); P[6] = w1.z * ca; Q[6] = w1.z * sa;
        __sincosf(a1.w, &sa, &ca); P[7] = w1.w * ca; Q[7] = w1.w * sa;
        #define ACC(p, q, s4v, c4v, Ur, Vr)                              \
            Ur[0] = fmaf(p, s4v.x, fmaf(-(q), c4v.x, Ur[0]));            \
            Vr[0] = fmaf(p, c4v.x, fmaf( (q), s4v.x, Vr[0]));            \
            Ur[1] = fmaf(p, s4v.y, fmaf(-(q), c4v.y, Ur[1]));            \
            Vr[1] = fmaf(p, c4v.y, fmaf( (q), s4v.y, Vr[1]));            \
            Ur[2] = fmaf(p, s4v.z, fmaf(-(q), c4v.z, Ur[2]));            \
            Vr[2] = fmaf(p, c4v.z, fmaf( (q), s4v.z, Vr[2]));            \
            Ur[3] = fmaf(p, s4v.w, fmaf(-(q), c4v.w, Ur[3]));            \
            Vr[3] = fmaf(p, c4v.w, fmaf( (q), s4v.w, Vr[3]));
        ACC(P[0], Q[0], s0, c0, U0, V0)
        ACC(P[1], Q[1], s1, c1, U0, V0)
        ACC(P[2], Q[2], s2, c2, U0, V0)
        ACC(P[3], Q[3], s3, c3, U0, V0)
        ACC(P[4], Q[4], s0, c0, U1, V1)
        ACC(P[5], Q[5], s1, c1, U1, V1)
        ACC(P[6], Q[6], s2, c2, U1, V1)
        ACC(P[7], Q[7], s3, c3, U1, V1)
        #undef ACC
    };

    float4 wA0, wA1, aA0, aA1, wX0, wX1, aX0, aX1;
    pf(0, wA0, wA1, aA0, aA1);

    for (int tile = 0; tile < kTiles; ++tile) {
        __syncthreads();                 // previous tile's LDS reads done
        stage_tile(tile);
        __syncthreads();
        const int g = tile * 4;
        pf(g + 1, wX0, wX1, aX0, aX1);
        __builtin_amdgcn_sched_barrier(0);
        compute(0, wA0, wA1, aA0, aA1);
        pf(g + 2, wA0, wA1, aA0, aA1);
        __builtin_amdgcn_sched_barrier(0);
        compute(1, wX0, wX1, aX0, aX1);
        pf(g + 3, wX0, wX1, aX0, aX1);
        __builtin_amdgcn_sched_barrier(0);
        compute(2, wA0, wA1, aA0, aA1);
        {
            const int gn = (g + 4 < kTotalStages) ? g + 4 : kTotalStages - 1;
            pf(gn, wA0, wA1, aA0, aA1);
        }
        __builtin_amdgcn_sched_barrier(0);
        compute(3, wX0, wX1, aX0, aX1);
    }

    // Wave-wide butterfly reduction (16 accumulators per wave).
    #pragma unroll
    for (int m = 1; m < 64; m <<= 1) {
        #pragma unroll
        for (int d = 0; d < kD; ++d) {
            U0[d] += __shfl_xor(U0[d], m, 64);
            V0[d] += __shfl_xor(V0[d], m, 64);
            U1[d] += __shfl_xor(U1[d], m, 64);
            V1[d] += __shfl_xor(V1[d], m, 64);
        }
    }

    #define EPILOG(LN, ROW, Ur, Vr)                                            \
        if (lane == LN) {                                                      \
            const int row = ROW;                                               \
            const float4 t4 = *reinterpret_cast<const float4*>(&theta[(size_t)row * kD]); \
            const float4 g4 = *reinterpret_cast<const float4*>(&gam[(size_t)row * kD]);   \
            const float tv[4] = {t4.x, t4.y, t4.z, t4.w};                      \
            const float gv[4] = {g4.x, g4.y, g4.z, g4.w};                      \
            constexpr float scale = 1.0f / (float)kN;                          \
            float x[4]; float nsq = 0.f;                                       \
            _Pragma("unroll")                                                  \
            for (int d = 0; d < kD; ++d) {                                     \
                float si, ci;                                                  \
                __sincosf(tv[d], &si, &ci);                                    \
                const float coup = scale * (ci * Ur[d] - si * Vr[d]);          \
                x[d] = gv[d] + coup;                                           \
                nsq += x[d] * x[d];                                            \
            }                                                                  \
            const float inv = 1.0f / fmaxf(sqrtf(nsq), 1e-6f);                 \
            float4 o;                                                          \
            o.x = x[0]*inv; o.y = x[1]*inv; o.z = x[2]*inv; o.w = x[3]*inv;    \
            *reinterpret_cast<float4*>(&out[(size_t)row * kD]) = o;            \
        }
    EPILOG(0, r0,     U0, V0)
    EPILOG(1, r0 + 1, U1, V1)
    #undef EPILOG
}

extern "C" void kernel_launch(void* const* d_in, const int* in_sizes, int n_in,
                              void* d_out, int out_size, void* d_ws, size_t ws_size,
                              hipStream_t stream) {
    const float* theta = (const float*)d_in[0];   // (B,N,D) f32
    const float* gam   = (const float*)d_in[1];   // (B,N,D) f32
    const float* W     = (const float*)d_in[2];   // (B,N,N) f32
    const float* alpha = (const float*)d_in[3];   // (B,N,N) f32
    float* out = (float*)d_out;                   // (B,N,D) f32

    const int totalRows = in_sizes[0] / kD;           // B*N = 8192
    const int nblocks = totalRows / kRowsPerBlock;    // 1024
    const size_t tabEntries = (size_t)kB * kN;        // 8192 float4 per table
    const size_t needWs = 2 * tabEntries * sizeof(float4);   // 256 KB

    if (ws_size >= needWs) {
        float4* sinT = (float4*)d_ws;
        float4* cosT = sinT + tabEntries;
        table_kernel<<<(int)(tabEntries / 256), 256, 0, stream>>>(theta, sinT, cosT);
        kuramoto_kernel<true><<<nblocks, kBlock, 0, stream>>>(
            theta, gam, W, alpha, sinT, cosT, out);
    } else {
        kuramoto_kernel<false><<<nblocks, kBlock, 0, stream>>>(
            theta, gam, W, alpha, nullptr, nullptr, out);
    }
}